// Round 3
// baseline (282.634 us; speedup 1.0000x reference)
//
#include <hip/hip_runtime.h>
#include <hip/hip_cooperative_groups.h>
#include <math.h>

// RMSELoss(early=1, gap=0.5, late=2), train=True path:
//   d = t - x ; v = d>=0.5 ? d^3 : (d<0 ? d^4 : 1) ; out = sqrt(mean(v))
//
// R4: NT loads 45.9->37 us. R5/R6/R7 (slab shaping, UNROLL 8, sc0sc1nt
// bypass): all flat => partial kernel sits at the PURE-READ ceiling
// (~3.6 TB/s; consistent with m13 copy = 6.29 TB/s COMBINED i.e. ~3.15
// TB/s/direction, while pure-write fill does 6.5). Fill writes through
// (its own window shows 268 MB WRITE_SIZE at HBM) so no dirty-L3
// writeback to dodge — R7's theory dead.
//
// R8 (this): the only non-wall slack left is launch structure. Fuse the
// two kernels with a cooperative launch + grid.sync(): kills the second
// kernel node (~2-3 us launch) and the final kernel (~3-4 us). Grid sized
// by occupancy query (co-residency guaranteed), grid-stride over chunks.
// Falls back to the proven two-kernel path if cooperative launch fails.

#define BLOCK  256
#define UNROLL 4
#define NWAVE  (BLOCK / 64)

namespace cg = cooperative_groups;

typedef float vfloat4 __attribute__((ext_vector_type(4)));

__device__ __forceinline__ float vfun(float d) {
    float d2 = d * d;
    float e  = d2 * d;   // d^3
    float l  = d2 * d2;  // d^4
    return d >= 0.5f ? e : (d < 0.0f ? l : 1.0f);
}

__device__ __forceinline__ float vfun4(vfloat4 a, vfloat4 b) {
    return vfun(b.x - a.x) + vfun(b.y - a.y) + vfun(b.z - a.z) + vfun(b.w - a.w);
}

// ---------------- fused cooperative kernel ----------------
__global__ __launch_bounds__(BLOCK) void rmse_fused(
        const vfloat4* __restrict__ x4,
        const vfloat4* __restrict__ t4,
        const float*  __restrict__ x,
        const float*  __restrict__ t,
        float* __restrict__ ws,
        float* __restrict__ out,
        float inv_n, int n4, int n, int nchunks) {
    const int chunk = BLOCK * UNROLL;          // 1024 float4 per chunk
    float acc0 = 0.0f, acc1 = 0.0f, acc2 = 0.0f, acc3 = 0.0f;

    for (int c = blockIdx.x; c < nchunks; c += gridDim.x) {
        int base = c * chunk + threadIdx.x;
        if ((c + 1) * chunk <= n4) {
            vfloat4 a[UNROLL], b[UNROLL];
            #pragma unroll
            for (int j = 0; j < UNROLL; ++j) {
                a[j] = __builtin_nontemporal_load(&x4[base + j * BLOCK]);
                b[j] = __builtin_nontemporal_load(&t4[base + j * BLOCK]);
            }
            acc0 += vfun4(a[0], b[0]);
            acc1 += vfun4(a[1], b[1]);
            acc2 += vfun4(a[2], b[2]);
            acc3 += vfun4(a[3], b[3]);
        } else {
            #pragma unroll
            for (int j = 0; j < UNROLL; ++j) {
                int i = base + j * BLOCK;
                if (i < n4)
                    acc0 += vfun4(__builtin_nontemporal_load(&x4[i]),
                                  __builtin_nontemporal_load(&t4[i]));
            }
        }
    }
    // scalar tail (n % 4)
    if (blockIdx.x == 0 && threadIdx.x == 0) {
        for (int j = n4 * 4; j < n; ++j) acc0 += vfun(t[j] - x[j]);
    }

    float acc = (acc0 + acc1) + (acc2 + acc3);

    // wave-64 reduction
    #pragma unroll
    for (int off = 32; off > 0; off >>= 1)
        acc += __shfl_down(acc, off, 64);

    __shared__ float smem[NWAVE];
    int lane = threadIdx.x & 63;
    int wave = threadIdx.x >> 6;
    if (lane == 0) smem[wave] = acc;
    __syncthreads();
    if (threadIdx.x == 0) {
        float s = 0.0f;
        #pragma unroll
        for (int w = 0; w < NWAVE; ++w) s += smem[w];
        ws[blockIdx.x] = s;
    }

    cg::this_grid().sync();   // device-scope fence + grid barrier

    if (blockIdx.x == 0) {
        float s = 0.0f;
        for (int i = threadIdx.x; i < (int)gridDim.x; i += BLOCK)
            s += ws[i];
        #pragma unroll
        for (int off = 32; off > 0; off >>= 1)
            s += __shfl_down(s, off, 64);
        __syncthreads();               // smem reuse hazard
        if (lane == 0) smem[wave] = s;
        __syncthreads();
        if (threadIdx.x == 0) {
            float tot = 0.0f;
            #pragma unroll
            for (int w = 0; w < NWAVE; ++w) tot += smem[w];
            out[0] = sqrtf(tot * inv_n);
        }
    }
}

// ---------------- fallback two-kernel path ----------------
__global__ __launch_bounds__(BLOCK) void rmse_partial(
        const vfloat4* __restrict__ x4,
        const vfloat4* __restrict__ t4,
        const float*  __restrict__ x,
        const float*  __restrict__ t,
        float* __restrict__ block_sums,
        int n4, int n) {
    const int chunk = BLOCK * UNROLL;
    int base = blockIdx.x * chunk + threadIdx.x;

    float acc0 = 0.0f, acc1 = 0.0f;

    if ((blockIdx.x + 1) * chunk <= n4) {
        vfloat4 a[UNROLL], b[UNROLL];
        #pragma unroll
        for (int j = 0; j < UNROLL; ++j) {
            a[j] = __builtin_nontemporal_load(&x4[base + j * BLOCK]);
            b[j] = __builtin_nontemporal_load(&t4[base + j * BLOCK]);
        }
        acc0 += vfun4(a[0], b[0]);
        acc1 += vfun4(a[1], b[1]);
        acc0 += vfun4(a[2], b[2]);
        acc1 += vfun4(a[3], b[3]);
    } else {
        #pragma unroll
        for (int j = 0; j < UNROLL; ++j) {
            int i = base + j * BLOCK;
            if (i < n4)
                acc0 += vfun4(__builtin_nontemporal_load(&x4[i]),
                              __builtin_nontemporal_load(&t4[i]));
        }
    }
    if (blockIdx.x == 0 && threadIdx.x == 0) {
        for (int j = n4 * 4; j < n; ++j) acc0 += vfun(t[j] - x[j]);
    }

    float acc = acc0 + acc1;

    #pragma unroll
    for (int off = 32; off > 0; off >>= 1)
        acc += __shfl_down(acc, off, 64);

    __shared__ float smem[NWAVE];
    int lane = threadIdx.x & 63;
    int wave = threadIdx.x >> 6;
    if (lane == 0) smem[wave] = acc;
    __syncthreads();
    if (threadIdx.x == 0) {
        float s = 0.0f;
        #pragma unroll
        for (int w = 0; w < NWAVE; ++w) s += smem[w];
        block_sums[blockIdx.x] = s;
    }
}

__global__ __launch_bounds__(1024) void rmse_final(
        const float* __restrict__ block_sums,
        float* __restrict__ out, float inv_n, int nb) {
    float s = 0.0f;
    for (int i = threadIdx.x; i < nb; i += 1024) s += block_sums[i];

    #pragma unroll
    for (int off = 32; off > 0; off >>= 1)
        s += __shfl_down(s, off, 64);

    __shared__ float smem[16];
    int lane = threadIdx.x & 63;
    int wave = threadIdx.x >> 6;
    if (lane == 0) smem[wave] = s;
    __syncthreads();
    if (threadIdx.x == 0) {
        float tot = 0.0f;
        #pragma unroll
        for (int w = 0; w < 16; ++w) tot += smem[w];
        out[0] = sqrtf(tot * inv_n);
    }
}

extern "C" void kernel_launch(void* const* d_in, const int* in_sizes, int n_in,
                              void* d_out, int out_size, void* d_ws, size_t ws_size,
                              hipStream_t stream) {
    const float* x = (const float*)d_in[0];   // inputs
    const float* t = (const float*)d_in[1];   // targets
    float* out = (float*)d_out;
    float* ws  = (float*)d_ws;

    int n  = in_sizes[0];
    int n4 = n / 4;

    const int chunk = BLOCK * UNROLL;              // 1024 float4 per chunk
    int nchunks = (n4 + chunk - 1) / chunk;        // 4096 at N=16Mi
    float inv_n = 1.0f / (float)n;

    // Co-resident capacity for the cooperative launch (cached; host-only
    // queries, safe under graph capture).
    static int coop_grid = -1;
    if (coop_grid < 0) {
        int dev = 0;
        hipGetDevice(&dev);
        hipDeviceProp_t prop;
        if (hipGetDeviceProperties(&prop, dev) == hipSuccess) {
            int mb = 0;
            if (hipOccupancyMaxActiveBlocksPerMultiprocessor(
                    &mb, (const void*)rmse_fused, BLOCK, 0) == hipSuccess && mb > 0)
                coop_grid = mb * prop.multiProcessorCount;
        }
        if (coop_grid <= 0) coop_grid = 0;   // mark "unavailable"
    }

    bool launched = false;
    if (coop_grid > 0) {
        int grid = nchunks < coop_grid ? nchunks : coop_grid;
        const vfloat4* x4p = (const vfloat4*)x;
        const vfloat4* t4p = (const vfloat4*)t;
        void* args[] = { (void*)&x4p, (void*)&t4p, (void*)&x, (void*)&t,
                         (void*)&ws, (void*)&out, (void*)&inv_n,
                         (void*)&n4, (void*)&n, (void*)&nchunks };
        hipError_t e = hipLaunchCooperativeKernel(
            (const void*)rmse_fused, dim3(grid), dim3(BLOCK), args, 0, stream);
        launched = (e == hipSuccess);
        if (!launched) coop_grid = 0;   // don't retry every call
    }

    if (!launched) {
        rmse_partial<<<nchunks, BLOCK, 0, stream>>>(
            (const vfloat4*)x, (const vfloat4*)t, x, t, ws, n4, n);
        rmse_final<<<1, 1024, 0, stream>>>(ws, out, inv_n, nchunks);
    }
}

// Round 4
// 137.534 us; speedup vs baseline: 2.0550x; 2.0550x over previous
//
#include <hip/hip_runtime.h>
#include <math.h>

// RMSELoss(early=1, gap=0.5, late=2), train=True path:
//   d = t - x ; v = d>=0.5 ? d^3 : (d<0 ? d^4 : 1) ; out = sqrt(mean(v))
//
// REVERT to R6 (best measured: 137.52 us). History:
//   R4: NT loads 45.9->37 us (partial). R5 slab-chunking: flat.
//   R6 UNROLL 4->8: flat (137.52). R7 sc0sc1nt full bypass: flat (138.3).
//   R8 cooperative fusion + grid.sync: 282 us REGRESSION — rmse_fused ran
//   244 us at 276 GB/s, 89% occupancy, 1.9% VALUBusy = grid.sync spin
//   pathology. Cooperative fusion is dead on this chip/harness.
// Ledger at 137.5: ~82 us harness poison-fills (fixed) + ~37 us partial
// (read wall ~3.6 TB/s — allocating/NT/bypass/unroll all converge) +
// ~4 us final + gaps. No remaining lever found.

#define BLOCK  256
#define UNROLL 8
#define NWAVE  (BLOCK / 64)

typedef float vfloat4 __attribute__((ext_vector_type(4)));

__device__ __forceinline__ float vfun(float d) {
    float d2 = d * d;
    float e  = d2 * d;   // d^3
    float l  = d2 * d2;  // d^4
    return d >= 0.5f ? e : (d < 0.0f ? l : 1.0f);
}

__device__ __forceinline__ float vfun4(vfloat4 a, vfloat4 b) {
    return vfun(b.x - a.x) + vfun(b.y - a.y) + vfun(b.z - a.z) + vfun(b.w - a.w);
}

__global__ __launch_bounds__(BLOCK) void rmse_partial(
        const vfloat4* __restrict__ x4,
        const vfloat4* __restrict__ t4,
        const float*  __restrict__ x,
        const float*  __restrict__ t,
        float* __restrict__ block_sums,
        int n4, int n) {
    const int chunk = BLOCK * UNROLL;          // 2048 float4 per block
    int base = blockIdx.x * chunk + threadIdx.x;

    float acc0 = 0.0f, acc1 = 0.0f, acc2 = 0.0f, acc3 = 0.0f;

    if ((blockIdx.x + 1) * chunk <= n4) {
        // Full chunk: 16 independent NT float4 loads, 32 KB contiguous
        // per array per block (64 KB slab total).
        vfloat4 a[UNROLL], b[UNROLL];
        #pragma unroll
        for (int j = 0; j < UNROLL; ++j) {
            a[j] = __builtin_nontemporal_load(&x4[base + j * BLOCK]);
            b[j] = __builtin_nontemporal_load(&t4[base + j * BLOCK]);
        }
        acc0 += vfun4(a[0], b[0]);
        acc1 += vfun4(a[1], b[1]);
        acc2 += vfun4(a[2], b[2]);
        acc3 += vfun4(a[3], b[3]);
        acc0 += vfun4(a[4], b[4]);
        acc1 += vfun4(a[5], b[5]);
        acc2 += vfun4(a[6], b[6]);
        acc3 += vfun4(a[7], b[7]);
    } else {
        // Last partial chunk (generality; empty at N=16Mi)
        #pragma unroll
        for (int j = 0; j < UNROLL; ++j) {
            int i = base + j * BLOCK;
            if (i < n4)
                acc0 += vfun4(__builtin_nontemporal_load(&x4[i]),
                              __builtin_nontemporal_load(&t4[i]));
        }
    }
    // scalar tail (n % 4)
    if (blockIdx.x == 0 && threadIdx.x == 0) {
        for (int j = n4 * 4; j < n; ++j) acc0 += vfun(t[j] - x[j]);
    }

    float acc = (acc0 + acc1) + (acc2 + acc3);

    // wave-64 reduction
    #pragma unroll
    for (int off = 32; off > 0; off >>= 1)
        acc += __shfl_down(acc, off, 64);

    __shared__ float smem[NWAVE];
    int lane = threadIdx.x & 63;
    int wave = threadIdx.x >> 6;
    if (lane == 0) smem[wave] = acc;
    __syncthreads();
    if (threadIdx.x == 0) {
        float s = 0.0f;
        #pragma unroll
        for (int w = 0; w < NWAVE; ++w) s += smem[w];
        block_sums[blockIdx.x] = s;   // every slot written — no memset needed
    }
}

__global__ __launch_bounds__(1024) void rmse_final(
        const float* __restrict__ block_sums,
        float* __restrict__ out, float inv_n, int nb) {
    float s = 0.0f;
    for (int i = threadIdx.x; i < nb; i += 1024) s += block_sums[i];

    #pragma unroll
    for (int off = 32; off > 0; off >>= 1)
        s += __shfl_down(s, off, 64);

    __shared__ float smem[16];
    int lane = threadIdx.x & 63;
    int wave = threadIdx.x >> 6;
    if (lane == 0) smem[wave] = s;
    __syncthreads();
    if (threadIdx.x == 0) {
        float tot = 0.0f;
        #pragma unroll
        for (int w = 0; w < 16; ++w) tot += smem[w];
        out[0] = sqrtf(tot * inv_n);
    }
}

extern "C" void kernel_launch(void* const* d_in, const int* in_sizes, int n_in,
                              void* d_out, int out_size, void* d_ws, size_t ws_size,
                              hipStream_t stream) {
    const float* x = (const float*)d_in[0];   // inputs
    const float* t = (const float*)d_in[1];   // targets
    float* out = (float*)d_out;
    float* ws  = (float*)d_ws;                // grid floats of partial sums

    int n  = in_sizes[0];
    int n4 = n / 4;

    const int chunk = BLOCK * UNROLL;          // 2048 float4 per block
    int grid = (n4 + chunk - 1) / chunk;       // 2048 at N=16Mi

    rmse_partial<<<grid, BLOCK, 0, stream>>>(
        (const vfloat4*)x, (const vfloat4*)t, x, t, ws, n4, n);

    rmse_final<<<1, 1024, 0, stream>>>(ws, out, 1.0f / (float)n, grid);
}